// Round 9
// baseline (172.072 us; speedup 1.0000x reference)
//
#include <hip/hip_runtime.h>
#include <math.h>

// Problem constants (fixed by setup_inputs: B=64, C=1, H=512, W=512 fp32)
static constexpr int Hdim = 512;
static constexpr int Wdim = 512;
static constexpr int HW   = Hdim * Wdim;       // 2^18 px per image
static constexpr int NIMG = 64;
static constexpr int WPR  = Wdim / 64;         // 8 uint64 words per row
static constexpr int WPI  = Hdim * WPR;        // 4096 words per image
static constexpr int TOTAL_WORDS = NIMG * WPI; // 262144 words (2 MB)
static constexpr int NBLK_A = 2048;            // mask kernel blocks (8192 waves)
static constexpr int GROUPS_PER_WAVE = 8;      // 8 x 256 px per wave
static constexpr int NBLK_B = TOTAL_WORDS / 256;  // 1024 boundary blocks
static constexpr int NBLK_C = 2048;            // main kernel blocks
static constexpr int CTHREADS = NBLK_C * 256;  // 524288
static constexpr int F4TOTAL = NIMG * HW / 4;  // 4194304 float4's
static constexpr int CITERS = F4TOTAL / CTHREADS;  // 8

// d_ws layout:
//   [0, 64KB):   per-block partials (NBLK_C slots x 8 floats, 5 used)
//   [1MB, 3MB):  tmask words (2 MB)
//   [4MB, 8MB):  comb: interleaved {tword, bword} pairs (4 MB)
// All regions fully overwritten each call; poison-safe.

typedef unsigned long long ull;

// 16-bit -> 64-bit spread by 4: bit m lands at bit 4m. All-uniform dataflow
// (ballot result is SGPR) so this should compile to scalar-pipe s_ops.
__device__ __forceinline__ ull spread4(ull x) {
    x = (x | (x << 24)) & 0x000000FF000000FFULL;
    x = (x | (x << 12)) & 0x000F000F000F000FULL;
    x = (x | (x << 6))  & 0x0303030303030303ULL;
    x = (x | (x << 3))  & 0x1111111111111111ULL;
    return x;
}

// ---- Kernel A: pack tgt>0.5 into bitmask. dwordx4 load + 4 ballots/group ----
__global__ __launch_bounds__(256) void mask_kernel(
    const float* __restrict__ tgt, ull* __restrict__ mask)
{
    const int lane = threadIdx.x & 63;
    const int wid  = (blockIdx.x * 256 + threadIdx.x) >> 6;   // 8192 waves
    const float4* t4 = (const float4*)tgt;
    #pragma unroll
    for (int g = 0; g < GROUPS_PER_WAVE; g++) {
        const int gg = wid * GROUPS_PER_WAVE + g;   // group of 256 px
        float4 v = t4[gg * 64 + lane];              // one dwordx4: 1 KB/wave
        ull b0 = __ballot(v.x > 0.5f);              // bit i = px 4i+0
        ull b1 = __ballot(v.y > 0.5f);
        ull b2 = __ballot(v.z > 0.5f);
        ull b3 = __ballot(v.w > 0.5f);
        // word w (64 px): bit j = ballot_{j&3} bit (16w + (j>>2))
        ull w0 =  spread4( b0        & 0xFFFF)       | (spread4( b1        & 0xFFFF) << 1)
               | (spread4( b2        & 0xFFFF) << 2) | (spread4( b3        & 0xFFFF) << 3);
        ull w1 =  spread4((b0 >> 16) & 0xFFFF)       | (spread4((b1 >> 16) & 0xFFFF) << 1)
               | (spread4((b2 >> 16) & 0xFFFF) << 2) | (spread4((b3 >> 16) & 0xFFFF) << 3);
        ull w2 =  spread4((b0 >> 32) & 0xFFFF)       | (spread4((b1 >> 32) & 0xFFFF) << 1)
               | (spread4((b2 >> 32) & 0xFFFF) << 2) | (spread4((b3 >> 32) & 0xFFFF) << 3);
        ull w3 =  spread4((b0 >> 48) & 0xFFFF)       | (spread4((b1 >> 48) & 0xFFFF) << 1)
               | (spread4((b2 >> 48) & 0xFFFF) << 2) | (spread4((b3 >> 48) & 0xFFFF) << 3);
        if (lane < 4) {
            ull val = (lane == 0) ? w0 : (lane == 1) ? w1 : (lane == 2) ? w2 : w3;
            mask[gg * 4 + lane] = val;              // 4 lanes x 8 B
        }
    }
}

__device__ __forceinline__ ull shl1(ull c, ull l) { return (c << 1) | (l >> 63); }
__device__ __forceinline__ ull shr1(ull c, ull r) { return (c >> 1) | (r << 63); }
__device__ __forceinline__ ull shl2(ull c, ull l) { return (c << 2) | (l >> 62); }
__device__ __forceinline__ ull shr2(ull c, ull r) { return (c >> 2) | (r << 62); }

// ---- Kernel B: word-parallel morphology; writes interleaved {tword,bword} ----
__global__ __launch_bounds__(256) void boundary_kernel(
    const ull* __restrict__ mask, ull* __restrict__ comb)
{
    const int w = blockIdx.x * 256 + threadIdx.x;   // global word id
    const int word = w & 7;                // column-word 0..7
    const int row  = (w >> 3) & (Hdim - 1);
    const ull* mi = mask + (w & ~(WPI - 1));  // image base

    #define FW(r, c) ((((unsigned)(r)) < (unsigned)Hdim && ((unsigned)(c)) < (unsigned)WPR) \
                        ? mi[((r) << 3) + (c)] : 0ULL)
    ull c0  = FW(row,     word);
    ull l0  = FW(row,     word - 1);
    ull rr0 = FW(row,     word + 1);
    ull cm  = FW(row - 1, word);
    ull lm  = FW(row - 1, word - 1);
    ull rm  = FW(row - 1, word + 1);
    ull cp  = FW(row + 1, word);
    ull lp  = FW(row + 1, word - 1);
    ull rp  = FW(row + 1, word + 1);
    ull cm2 = FW(row - 2, word);
    ull cp2 = FW(row + 2, word);
    #undef FW

    ull er =
        c0 & shl1(c0,l0) & shr1(c0,rr0) & shl2(c0,l0) & shr2(c0,rr0)
           & cm & shl1(cm,lm) & shr1(cm,rm)
           & cp & shl1(cp,lp) & shr1(cp,rp)
           & cm2 & cp2;
    ull di =
        c0 | shl1(c0,l0) | shr1(c0,rr0) | shl2(c0,l0) | shr2(c0,rr0)
           | cm | shl1(cm,lm) | shr1(cm,rm)
           | cp | shl1(cp,lp) | shr1(cp,rp)
           | cm2 | cp2;

    comb[2 * w]     = c0;          // t-word
    comb[2 * w + 1] = di & ~er;    // boundary word
}

// ---- Kernel C: pure streaming elementwise + per-block partials ----
__global__ __launch_bounds__(256, 4) void combined_loss_kernel(
    const float* __restrict__ inp, const ulonglong2* __restrict__ comb,
    float* __restrict__ partials)
{
    const int tid = blockIdx.x * 256 + threadIdx.x;
    float s_focal = 0.f, s_inter = 0.f, s_p = 0.f, s_bw = 0.f;
    int s_tc = 0;

    #pragma unroll
    for (int it = 0; it < CITERS; it++) {
        const int f4 = tid + it * CTHREADS;
        const float4 v = ((const float4*)inp)[f4];
        const int wi = f4 >> 4;              // mask word index
        const int sh = (f4 & 15) * 4;        // nibble shift
        const ulonglong2 cb = comb[wi];      // one 16B load: {tword, bword}
        unsigned int tb4 = (unsigned int)((cb.x >> sh) & 0xFULL);
        unsigned int bb4 = (unsigned int)((cb.y >> sh) & 0xFULL);
        s_tc += __popc(tb4);
        const float xs[4] = {v.x, v.y, v.z, v.w};
        #pragma unroll
        for (int k = 0; k < 4; k++) {
            float xi = xs[k];
            bool tpos = (tb4 >> k) & 1;
            float e  = __expf(-fabsf(xi));                  // exp(-|x|)
            float bce = fmaxf(xi, 0.f) - (tpos ? xi : 0.f) + __logf(1.f + e);
            float rden = __builtin_amdgcn_rcpf(1.f + e);
            float p = (xi >= 0.f ? 1.f : e) * rden;         // sigmoid
            float pt = tpos ? p : 1.f - p;                  // == exp(-bce)
            float om = 1.f - pt;
            s_focal += 0.25f * om * om * bce;
            s_p     += p;
            s_inter += tpos ? p : 0.f;
            float wgt = ((bb4 >> k) & 1) ? 6.0f : 1.0f;     // 1 + THETA*boundary
            s_bw += bce * wgt;
        }
    }
    float s_t = (float)s_tc;

    // Reduce: wave shuffle -> LDS -> per-block partial store (NO atomics)
    __shared__ float smem[4][5];
    const int wave = threadIdx.x >> 6;
    const int lane = threadIdx.x & 63;
    #pragma unroll
    for (int off = 32; off > 0; off >>= 1) {
        s_focal += __shfl_down(s_focal, off);
        s_inter += __shfl_down(s_inter, off);
        s_p     += __shfl_down(s_p,     off);
        s_t     += __shfl_down(s_t,     off);
        s_bw    += __shfl_down(s_bw,    off);
    }
    if (lane == 0) {
        smem[wave][0] = s_focal; smem[wave][1] = s_inter; smem[wave][2] = s_p;
        smem[wave][3] = s_t;     smem[wave][4] = s_bw;
    }
    __syncthreads();
    if (threadIdx.x < 5) {
        float a = smem[0][threadIdx.x] + smem[1][threadIdx.x]
                + smem[2][threadIdx.x] + smem[3][threadIdx.x];
        partials[blockIdx.x * 8 + threadIdx.x] = a;
    }
}

// ---- Kernel D: reduce NBLK_C partial slots, compute final scalar ----
__global__ __launch_bounds__(256) void finalize_kernel(
    const float* __restrict__ partials, float* __restrict__ out)
{
    __shared__ float smem[4][5];
    float a0 = 0.f, a1 = 0.f, a2 = 0.f, a3 = 0.f, a4 = 0.f;
    for (int b = threadIdx.x; b < NBLK_C; b += 256) {
        const float* s = partials + b * 8;
        a0 += s[0]; a1 += s[1]; a2 += s[2]; a3 += s[3]; a4 += s[4];
    }
    #pragma unroll
    for (int off = 32; off > 0; off >>= 1) {
        a0 += __shfl_down(a0, off);
        a1 += __shfl_down(a1, off);
        a2 += __shfl_down(a2, off);
        a3 += __shfl_down(a3, off);
        a4 += __shfl_down(a4, off);
    }
    int wave = threadIdx.x >> 6;
    int lane = threadIdx.x & 63;
    if (lane == 0) {
        smem[wave][0] = a0; smem[wave][1] = a1; smem[wave][2] = a2;
        smem[wave][3] = a3; smem[wave][4] = a4;
    }
    __syncthreads();
    if (threadIdx.x == 0) {
        double b0 = 0, b1 = 0, b2 = 0, b3 = 0, b4 = 0;
        #pragma unroll
        for (int w = 0; w < 4; w++) {
            b0 += smem[w][0]; b1 += smem[w][1]; b2 += smem[w][2];
            b3 += smem[w][3]; b4 += smem[w][4];
        }
        double invN = 1.0 / (double)(NIMG * HW);
        double focal_loss = b0 * invN;
        double dice = (2.0 * b1 + 1e-6) / (b2 + b3 + 1e-6);
        double boundary_loss = b4 * invN;
        out[0] = (float)(0.3 * focal_loss + 0.4 * (1.0 - dice) + 0.3 * boundary_loss);
    }
}

extern "C" void kernel_launch(void* const* d_in, const int* in_sizes, int n_in,
                              void* d_out, int out_size, void* d_ws, size_t ws_size,
                              hipStream_t stream) {
    const float* inp = (const float*)d_in[0];
    const float* tgt = (const float*)d_in[1];
    float* out = (float*)d_out;
    char* ws = (char*)d_ws;
    float* partials = (float*)ws;
    ull* tmask = (ull*)(ws + (1u << 20));
    ull* comb  = (ull*)(ws + (4u << 20));

    mask_kernel<<<NBLK_A, 256, 0, stream>>>(tgt, tmask);
    boundary_kernel<<<NBLK_B, 256, 0, stream>>>(tmask, comb);
    combined_loss_kernel<<<NBLK_C, 256, 0, stream>>>(inp, (const ulonglong2*)comb, partials);
    finalize_kernel<<<1, 256, 0, stream>>>(partials, out);
}

// Round 10
// 153.783 us; speedup vs baseline: 1.1189x; 1.1189x over previous
//
#include <hip/hip_runtime.h>
#include <math.h>

// Problem constants (fixed by setup_inputs: B=64, C=1, H=512, W=512 fp32)
static constexpr int Hdim = 512;
static constexpr int Wdim = 512;
static constexpr int HW   = Hdim * Wdim;       // 2^18 px per image
static constexpr int NIMG = 64;
static constexpr int GPR  = Wdim / 256;        // 2 groups (256 px) per row
static constexpr int GPI  = Hdim * GPR;        // 1024 groups per image
static constexpr int NGRP = NIMG * GPI;        // 65536 groups total
static constexpr int NBLK_A = 2048;            // mask kernel blocks (8192 waves)
static constexpr int GROUPS_PER_WAVE = 8;
static constexpr int NBLK_B = NGRP / 256;      // 256 boundary blocks
static constexpr int NBLK_C = 2048;            // main kernel blocks
static constexpr int CTHREADS = NBLK_C * 256;  // 524288
static constexpr int F4TOTAL = NIMG * HW / 4;  // 4194304 float4's
static constexpr int CITERS = F4TOTAL / CTHREADS;  // 8

// d_ws layout:
//   [0, 64KB):   per-block partials (NBLK_C slots x 8 floats, 5 used)
//   [1MB, 3MB):  plane mask: 4 ull per 256-px group (2 MB)
//   [4MB, 8MB):  comb8: 1 byte per 4 px = t-nibble | b-nibble<<4 (4 MB)
// All regions fully overwritten each call; poison-safe.

typedef unsigned long long ull;

// ---- Kernel A: ballot-native plane mask. Plane k bit i = px(group*256+4i+k) ----
__global__ __launch_bounds__(256) void mask_kernel(
    const float* __restrict__ tgt, ull* __restrict__ mask)
{
    const int lane = threadIdx.x & 63;
    const int wid  = (blockIdx.x * 256 + threadIdx.x) >> 6;   // 8192 waves
    const float4* t4 = (const float4*)tgt;
    #pragma unroll
    for (int g = 0; g < GROUPS_PER_WAVE; g++) {
        const int gg = wid * GROUPS_PER_WAVE + g;   // group of 256 px
        float4 v = t4[gg * 64 + lane];              // one dwordx4: 1 KB/wave
        ull p0 = __ballot(v.x > 0.5f);
        ull p1 = __ballot(v.y > 0.5f);
        ull p2 = __ballot(v.z > 0.5f);
        ull p3 = __ballot(v.w > 0.5f);
        if (lane == 0) {
            ulonglong2* mp = (ulonglong2*)(mask + gg * 4);
            ulonglong2 a; a.x = p0; a.y = p1;
            ulonglong2 b; b.x = p2; b.y = p3;
            mp[0] = a;                              // 2 x 16B stores
            mp[1] = b;
        }
    }
}

// 8-bit -> 64-bit spread: input bit j -> output bit 8j
__device__ __forceinline__ ull spread8(ull x) {
    x = (x | (x << 28)) & 0x0000000F0000000FULL;
    x = (x | (x << 14)) & 0x0003000300030003ULL;
    x = (x | (x << 7))  & 0x0101010101010101ULL;
    return x;
}

struct PlaneRow { ull p0, p1, p2, p3, lc2, lc3, rc0, rc1; };

// ---- Kernel B: plane-formulated radius-2 diamond morphology + byte transpose ----
__global__ __launch_bounds__(256) void boundary_kernel(
    const ull* __restrict__ mask, ull* __restrict__ combq)
{
    const int gg   = blockIdx.x * 256 + threadIdx.x;  // group id
    const int img  = gg >> 10;                        // / GPI
    const int gi   = gg & (GPI - 1);
    const int row  = gi >> 1;                         // image row
    const int side = gi & 1;                          // 0 = left half, 1 = right half
    const ull* ib = mask + img * GPI * 4;

    // Load plane rows r-2..r+2 (own planes; halo carries from the other side-group)
    PlaneRow pr[5];
    #pragma unroll
    for (int d = 0; d < 5; d++) {
        int rho = row + d - 2;
        PlaneRow P;
        if ((unsigned)rho < (unsigned)Hdim) {
            const ull* ob = ib + (rho * GPR + side) * 4;
            ulonglong2 a = ((const ulonglong2*)ob)[0];
            ulonglong2 b = ((const ulonglong2*)ob)[1];
            P.p0 = a.x; P.p1 = a.y; P.p2 = b.x; P.p3 = b.y;
            if (side == 1) {                 // left neighbor exists
                const ull* lb = ib + (rho * GPR + 0) * 4;
                ulonglong2 c = ((const ulonglong2*)lb)[1];   // P2,P3
                P.lc2 = c.x; P.lc3 = c.y;
            } else { P.lc2 = 0; P.lc3 = 0; }
            if (side == 0) {                 // right neighbor exists
                const ull* rb = ib + (rho * GPR + 1) * 4;
                ulonglong2 c = ((const ulonglong2*)rb)[0];   // P0,P1
                P.rc0 = c.x; P.rc1 = c.y;
            } else { P.rc0 = 0; P.rc1 = 0; }
        } else {
            P.p0 = P.p1 = P.p2 = P.p3 = 0; P.lc2 = P.lc3 = 0; P.rc0 = P.rc1 = 0;
        }
        pr[d] = P;
    }

    // A terms (c & x+1 & x-1) for rows r-1, r, r+1; AND and OR variants
    ull Aa[3][4], Ao[3][4];
    #pragma unroll
    for (int j = 0; j < 3; j++) {
        const PlaneRow& P = pr[j + 1];
        ull m0 = (P.p3 << 1) | (P.lc3 >> 63);   // x-1 for plane 0
        ull m3 = (P.p0 >> 1) | (P.rc0 << 63);   // x+1 for plane 3
        Aa[j][0] = P.p0 & P.p1 & m0;  Ao[j][0] = P.p0 | P.p1 | m0;
        Aa[j][1] = P.p1 & P.p2 & P.p0; Ao[j][1] = P.p1 | P.p2 | P.p0;
        Aa[j][2] = P.p2 & P.p3 & P.p1; Ao[j][2] = P.p2 | P.p3 | P.p1;
        Aa[j][3] = P.p3 & m3 & P.p2;  Ao[j][3] = P.p3 | m3 | P.p2;
    }
    // B terms (x+2 & x-2) for center row
    ull Ba[4], Bo[4];
    {
        const PlaneRow& P = pr[2];
        ull b0m = (P.p2 << 1) | (P.lc2 >> 63);
        ull b1m = (P.p3 << 1) | (P.lc3 >> 63);
        ull b2m = (P.p0 >> 1) | (P.rc0 << 63);
        ull b3m = (P.p1 >> 1) | (P.rc1 << 63);
        Ba[0] = P.p2 & b0m;  Bo[0] = P.p2 | b0m;
        Ba[1] = P.p3 & b1m;  Bo[1] = P.p3 | b1m;
        Ba[2] = P.p0 & b2m;  Bo[2] = P.p0 | b2m;
        Ba[3] = P.p1 & b3m;  Bo[3] = P.p1 | b3m;
    }
    const ull Cm2[4] = { pr[0].p0, pr[0].p1, pr[0].p2, pr[0].p3 };
    const ull Cp2[4] = { pr[4].p0, pr[4].p1, pr[4].p2, pr[4].p3 };
    const ull T[4]   = { pr[2].p0, pr[2].p1, pr[2].p2, pr[2].p3 };

    ull B[4];
    #pragma unroll
    for (int k = 0; k < 4; k++) {
        ull er = Aa[0][k] & Aa[1][k] & Aa[2][k] & Ba[k] & Cm2[k] & Cp2[k];
        ull di = Ao[0][k] | Ao[1][k] | Ao[2][k] | Bo[k] | Cm2[k] | Cp2[k];
        B[k] = di & ~er;
    }

    // Transpose planes -> 64 bytes: byte i = t-nibble(px 4i..4i+3) | b-nibble<<4
    ull* outp = combq + gg * 8;
    #pragma unroll
    for (int q = 0; q < 8; q++) {
        ull o = spread8((T[0] >> (8 * q)) & 0xFF)
              | (spread8((T[1] >> (8 * q)) & 0xFF) << 1)
              | (spread8((T[2] >> (8 * q)) & 0xFF) << 2)
              | (spread8((T[3] >> (8 * q)) & 0xFF) << 3)
              | (spread8((B[0] >> (8 * q)) & 0xFF) << 4)
              | (spread8((B[1] >> (8 * q)) & 0xFF) << 5)
              | (spread8((B[2] >> (8 * q)) & 0xFF) << 6)
              | (spread8((B[3] >> (8 * q)) & 0xFF) << 7);
        outp[q] = o;
    }
}

// ---- Kernel C: pure streaming elementwise + per-block partials ----
__global__ __launch_bounds__(256, 4) void combined_loss_kernel(
    const float* __restrict__ inp, const unsigned char* __restrict__ comb8,
    float* __restrict__ partials)
{
    const int tid = blockIdx.x * 256 + threadIdx.x;
    float s_focal = 0.f, s_inter = 0.f, s_p = 0.f, s_bw = 0.f;
    int s_tc = 0;

    #pragma unroll
    for (int it = 0; it < CITERS; it++) {
        const int f4 = tid + it * CTHREADS;
        const float4 v = ((const float4*)inp)[f4];
        const unsigned int c = comb8[f4];    // 1-byte load: t|b<<4 for these 4 px
        const unsigned int tb4 = c & 0xF;
        const unsigned int bb4 = c >> 4;
        s_tc += __popc(tb4);
        const float xs[4] = {v.x, v.y, v.z, v.w};
        #pragma unroll
        for (int k = 0; k < 4; k++) {
            float xi = xs[k];
            bool tpos = (tb4 >> k) & 1;
            float e  = __expf(-fabsf(xi));                  // exp(-|x|)
            float bce = fmaxf(xi, 0.f) - (tpos ? xi : 0.f) + __logf(1.f + e);
            float rden = __builtin_amdgcn_rcpf(1.f + e);
            float p = (xi >= 0.f ? 1.f : e) * rden;         // sigmoid
            float pt = tpos ? p : 1.f - p;                  // == exp(-bce)
            float om = 1.f - pt;
            s_focal += 0.25f * om * om * bce;
            s_p     += p;
            s_inter += tpos ? p : 0.f;
            float wgt = ((bb4 >> k) & 1) ? 6.0f : 1.0f;     // 1 + THETA*boundary
            s_bw += bce * wgt;
        }
    }
    float s_t = (float)s_tc;

    // Reduce: wave shuffle -> LDS -> per-block partial store (NO atomics)
    __shared__ float smem[4][5];
    const int wave = threadIdx.x >> 6;
    const int lane = threadIdx.x & 63;
    #pragma unroll
    for (int off = 32; off > 0; off >>= 1) {
        s_focal += __shfl_down(s_focal, off);
        s_inter += __shfl_down(s_inter, off);
        s_p     += __shfl_down(s_p,     off);
        s_t     += __shfl_down(s_t,     off);
        s_bw    += __shfl_down(s_bw,    off);
    }
    if (lane == 0) {
        smem[wave][0] = s_focal; smem[wave][1] = s_inter; smem[wave][2] = s_p;
        smem[wave][3] = s_t;     smem[wave][4] = s_bw;
    }
    __syncthreads();
    if (threadIdx.x < 5) {
        float a = smem[0][threadIdx.x] + smem[1][threadIdx.x]
                + smem[2][threadIdx.x] + smem[3][threadIdx.x];
        partials[blockIdx.x * 8 + threadIdx.x] = a;
    }
}

// ---- Kernel D: reduce NBLK_C partial slots, compute final scalar ----
__global__ __launch_bounds__(256) void finalize_kernel(
    const float* __restrict__ partials, float* __restrict__ out)
{
    __shared__ float smem[4][5];
    float a0 = 0.f, a1 = 0.f, a2 = 0.f, a3 = 0.f, a4 = 0.f;
    for (int b = threadIdx.x; b < NBLK_C; b += 256) {
        const float* s = partials + b * 8;
        a0 += s[0]; a1 += s[1]; a2 += s[2]; a3 += s[3]; a4 += s[4];
    }
    #pragma unroll
    for (int off = 32; off > 0; off >>= 1) {
        a0 += __shfl_down(a0, off);
        a1 += __shfl_down(a1, off);
        a2 += __shfl_down(a2, off);
        a3 += __shfl_down(a3, off);
        a4 += __shfl_down(a4, off);
    }
    int wave = threadIdx.x >> 6;
    int lane = threadIdx.x & 63;
    if (lane == 0) {
        smem[wave][0] = a0; smem[wave][1] = a1; smem[wave][2] = a2;
        smem[wave][3] = a3; smem[wave][4] = a4;
    }
    __syncthreads();
    if (threadIdx.x == 0) {
        double b0 = 0, b1 = 0, b2 = 0, b3 = 0, b4 = 0;
        #pragma unroll
        for (int w = 0; w < 4; w++) {
            b0 += smem[w][0]; b1 += smem[w][1]; b2 += smem[w][2];
            b3 += smem[w][3]; b4 += smem[w][4];
        }
        double invN = 1.0 / (double)(NIMG * HW);
        double focal_loss = b0 * invN;
        double dice = (2.0 * b1 + 1e-6) / (b2 + b3 + 1e-6);
        double boundary_loss = b4 * invN;
        out[0] = (float)(0.3 * focal_loss + 0.4 * (1.0 - dice) + 0.3 * boundary_loss);
    }
}

extern "C" void kernel_launch(void* const* d_in, const int* in_sizes, int n_in,
                              void* d_out, int out_size, void* d_ws, size_t ws_size,
                              hipStream_t stream) {
    const float* inp = (const float*)d_in[0];
    const float* tgt = (const float*)d_in[1];
    float* out = (float*)d_out;
    char* ws = (char*)d_ws;
    float* partials = (float*)ws;
    ull* mask  = (ull*)(ws + (1u << 20));
    ull* combq = (ull*)(ws + (4u << 20));

    mask_kernel<<<NBLK_A, 256, 0, stream>>>(tgt, mask);
    boundary_kernel<<<NBLK_B, 256, 0, stream>>>(mask, combq);
    combined_loss_kernel<<<NBLK_C, 256, 0, stream>>>(inp, (const unsigned char*)combq, partials);
    finalize_kernel<<<1, 256, 0, stream>>>(partials, out);
}